// Round 1
// baseline (1751.347 us; speedup 1.0000x reference)
//
#include <hip/hip_runtime.h>
#include <math.h>

#define NB 16384
#define ND 512
#define NE 16
#define NH 2048
#define LN_EPS 1e-5f
#define TM 32   // rows per block in MLP kernel

// ws layout (bytes):
//   [0, NB*4)                : mu (float per row)
//   [NB*4, 2*NB*4)           : rstd (float per row)
//   [2*NB*4, 2*NB*4+64)      : counts (NE ints, padded)
//   [2*NB*4+256, +NE*NB*4)   : rows (per-expert row lists, NE x NB ints)
#define WS_MU_OFF    0
#define WS_RSTD_OFF  (NB * 4)
#define WS_CNT_OFF   (2 * NB * 4)
#define WS_ROWS_OFF  (2 * NB * 4 + 256)

// ---------------- Kernel 1: gate + softmax + argmax scatter + LN stats ----
// One wave (64 lanes) per row; 4 waves per block.
__global__ __launch_bounds__(256) void gate_ln_kernel(
    const float* __restrict__ z, const float* __restrict__ gw,
    const float* __restrict__ gb, float* __restrict__ mu_out,
    float* __restrict__ rstd_out, int* __restrict__ counts,
    int* __restrict__ rows, float* __restrict__ g_out)
{
    int wave = threadIdx.x >> 6;
    int lane = threadIdx.x & 63;
    int b = blockIdx.x * 4 + wave;
    if (b >= NB) return;

    const float* zr = z + (size_t)b * ND;
    float4 za = *reinterpret_cast<const float4*>(zr + lane * 8);
    float4 zb = *reinterpret_cast<const float4*>(zr + lane * 8 + 4);
    float zv[8] = {za.x, za.y, za.z, za.w, zb.x, zb.y, zb.z, zb.w};

    float sum = 0.f, ssq = 0.f;
#pragma unroll
    for (int k = 0; k < 8; ++k) { sum += zv[k]; ssq += zv[k] * zv[k]; }

    float acc[NE];
#pragma unroll
    for (int e = 0; e < NE; ++e) acc[e] = 0.f;

#pragma unroll
    for (int k = 0; k < 8; ++k) {
        int d = lane * 8 + k;
        const float4* gwp = reinterpret_cast<const float4*>(gw + d * NE);
        float4 q0 = gwp[0], q1 = gwp[1], q2 = gwp[2], q3 = gwp[3];
        float gvec[NE] = {q0.x, q0.y, q0.z, q0.w, q1.x, q1.y, q1.z, q1.w,
                          q2.x, q2.y, q2.z, q2.w, q3.x, q3.y, q3.z, q3.w};
        float zk = zv[k];
#pragma unroll
        for (int e = 0; e < NE; ++e) acc[e] = fmaf(zk, gvec[e], acc[e]);
    }

    // butterfly reduce across 64 lanes (sum, ssq, 16 gate accs)
#pragma unroll
    for (int m = 32; m >= 1; m >>= 1) {
        sum += __shfl_xor(sum, m);
        ssq += __shfl_xor(ssq, m);
#pragma unroll
        for (int e = 0; e < NE; ++e) acc[e] += __shfl_xor(acc[e], m);
    }

    float mu = sum * (1.f / ND);
    float var = ssq * (1.f / ND) - mu * mu;
    float rstd = rsqrtf(var + LN_EPS);

    // softmax over 16 (all lanes hold identical acc[])
    float mx = -1e30f;
#pragma unroll
    for (int e = 0; e < NE; ++e) { acc[e] += gb[e]; mx = fmaxf(mx, acc[e]); }
    float den = 0.f;
#pragma unroll
    for (int e = 0; e < NE; ++e) { acc[e] = __expf(acc[e] - mx); den += acc[e]; }
    float rden = 1.f / den;
#pragma unroll
    for (int e = 0; e < NE; ++e) acc[e] *= rden;

    // argmax, first occurrence of max (matches jnp.argmax)
    int idx = 0; float best = acc[0];
#pragma unroll
    for (int e = 1; e < NE; ++e) { if (acc[e] > best) { best = acc[e]; idx = e; } }

    // coalesced g write: lane e (<16) writes g[b][e] via cndmask select chain
    float gval = acc[0];
#pragma unroll
    for (int e = 1; e < NE; ++e) if (lane == e) gval = acc[e];
    if (lane < NE) g_out[(size_t)b * NE + lane] = gval;

    if (lane == 0) {
        mu_out[b] = mu;
        rstd_out[b] = rstd;
        int pos = atomicAdd(counts + idx, 1);
        rows[(size_t)idx * NB + pos] = b;
    }
}

// ---------------- Kernel 2: bucketed expert MLP ---------------------------
// grid = (NB/TM, NE). Block (t, e) handles rows [t*TM, t*TM+TM) of bucket e.
// 256 threads = 8 row-groups (tr, 4 rows each) x 32 col-threads (tc, 8 cols).
__global__ __launch_bounds__(256, 2) void mlp_kernel(
    const float* __restrict__ z, const float* __restrict__ ln_s,
    const float* __restrict__ ln_b, const float* __restrict__ w1,
    const float* __restrict__ b1, const float* __restrict__ w2,
    const float* __restrict__ b2, const float* __restrict__ mu,
    const float* __restrict__ rstd, const int* __restrict__ counts,
    const int* __restrict__ rows, float* __restrict__ logits)
{
    __shared__ float xs[TM][ND];   // 64 KiB

    int e = blockIdx.y;
    int cnt = counts[e];
    int base = blockIdx.x * TM;
    if (base >= cnt) return;
    int nr = min(TM, cnt - base);

    const int* rl = rows + (size_t)e * NB + base;
    int tid = threadIdx.x;
    const float* lns = ln_s + e * ND;
    const float* lnb = ln_b + e * ND;

    // stage normalized+affined activations
    for (int i = tid; i < nr * ND; i += 256) {
        int r = i >> 9;            // /ND
        int d = i & (ND - 1);
        int row = rl[r];
        float zz = z[(size_t)row * ND + d];
        xs[r][d] = (zz - mu[row]) * rstd[row] * lns[d] + lnb[d];
    }
    __syncthreads();

    int tr = tid >> 5;   // 0..7  -> rows tr*4 .. tr*4+3
    int tc = tid & 31;   // 0..31 -> cols pass*256 + tc*8 .. +7

    const float* w1e = w1 + (size_t)e * ND * NH;
    const float* b1e = b1 + (size_t)e * NH;
    const float* w2e = w2 + (size_t)e * NH;

    float o[4] = {0.f, 0.f, 0.f, 0.f};

    for (int pass = 0; pass < 8; ++pass) {
        int j0 = pass * 256 + tc * 8;
        float acc[4][8];
#pragma unroll
        for (int r = 0; r < 4; ++r)
#pragma unroll
            for (int k = 0; k < 8; ++k) acc[r][k] = 0.f;

        const float* wp = w1e + j0;
#pragma unroll 2
        for (int d = 0; d < ND; ++d) {
            float4 wa = *reinterpret_cast<const float4*>(wp);
            float4 wb = *reinterpret_cast<const float4*>(wp + 4);
            wp += NH;
            float wv[8] = {wa.x, wa.y, wa.z, wa.w, wb.x, wb.y, wb.z, wb.w};
            float xv[4];
#pragma unroll
            for (int r = 0; r < 4; ++r) xv[r] = xs[tr * 4 + r][d];
#pragma unroll
            for (int r = 0; r < 4; ++r)
#pragma unroll
                for (int k = 0; k < 8; ++k)
                    acc[r][k] = fmaf(xv[r], wv[k], acc[r][k]);
        }

        // epilogue: bias + exact gelu + w2 accumulate
#pragma unroll
        for (int k = 0; k < 8; ++k) {
            float b1v = b1e[j0 + k];
            float w2v = w2e[j0 + k];
#pragma unroll
            for (int r = 0; r < 4; ++r) {
                float h = acc[r][k] + b1v;
                float gl = 0.5f * h * (1.f + erff(h * 0.70710678118f));
                o[r] = fmaf(gl, w2v, o[r]);
            }
        }
    }

    // reduce o over the 32 col-threads (low 5 lane bits)
#pragma unroll
    for (int m = 16; m >= 1; m >>= 1) {
#pragma unroll
        for (int r = 0; r < 4; ++r) o[r] += __shfl_xor(o[r], m);
    }

    if (tc == 0) {
        float bb = b2[e];
#pragma unroll
        for (int r = 0; r < 4; ++r) {
            int rr = tr * 4 + r;
            if (rr < nr) logits[rl[rr]] = o[r] + bb;
        }
    }
}

extern "C" void kernel_launch(void* const* d_in, const int* in_sizes, int n_in,
                              void* d_out, int out_size, void* d_ws, size_t ws_size,
                              hipStream_t stream) {
    const float* z    = (const float*)d_in[0];
    const float* gw   = (const float*)d_in[1];
    const float* gb   = (const float*)d_in[2];
    const float* ln_s = (const float*)d_in[3];
    const float* ln_b = (const float*)d_in[4];
    const float* w1   = (const float*)d_in[5];
    const float* b1   = (const float*)d_in[6];
    const float* w2   = (const float*)d_in[7];
    const float* b2   = (const float*)d_in[8];

    float* logits = (float*)d_out;            // [NB]
    float* g_out  = (float*)d_out + NB;       // [NB, NE]

    char* ws = (char*)d_ws;
    float* mu    = (float*)(ws + WS_MU_OFF);
    float* rstd  = (float*)(ws + WS_RSTD_OFF);
    int*   cnts  = (int*)(ws + WS_CNT_OFF);
    int*   rows  = (int*)(ws + WS_ROWS_OFF);

    // counts must be zero every call (ws is not re-poisoned between replays)
    hipMemsetAsync(cnts, 0, NE * sizeof(int), stream);

    gate_ln_kernel<<<NB / 4, 256, 0, stream>>>(z, gw, gb, mu, rstd, cnts, rows, g_out);

    dim3 grid2(NB / TM, NE);
    mlp_kernel<<<grid2, 256, 0, stream>>>(z, ln_s, ln_b, w1, b1, w2, b2,
                                          mu, rstd, cnts, rows, logits);
}

// Round 2
// 414.507 us; speedup vs baseline: 4.2251x; 4.2251x over previous
//
#include <hip/hip_runtime.h>
#include <math.h>

#define NB 16384
#define ND 512
#define NE 16
#define NH 2048
#define CW 128            // cols per chunk in mfma_mlp
#define NCH (NH / CW)     // 16 chunks
#define LN_EPS 1e-5f

typedef __attribute__((ext_vector_type(8))) short s8v;   // 8 bf16 (4 VGPR)
typedef __attribute__((ext_vector_type(4))) float f4v;   // mfma 16x16 acc

// ---- ws layout (bytes) ----
// w1t: bf16, per (e,chunk) slice [CW cols][ND k] contiguous = 131072 B
#define WS_W1T_OFF   ((size_t)0)
#define WS_W1T_BYTES ((size_t)NE * NH * ND * 2)                  // 32 MiB
#define WS_XN_OFF    (WS_W1T_OFF + WS_W1T_BYTES)
#define WS_XN_BYTES  ((size_t)NB * ND * 2)                       // 16 MiB
#define WS_CNT_OFF   (WS_XN_OFF + WS_XN_BYTES)
#define WS_ROWS_OFF  (WS_CNT_OFF + 256)

__device__ __forceinline__ unsigned short bf16_rne(float f) {
    unsigned u = __float_as_uint(f);
    unsigned r = (u + 0x7fffu + ((u >> 16) & 1u)) >> 16;
    return (unsigned short)r;
}

// ---------------- Kernel 1: gate + softmax + argmax + LN + xn(bf16) -------
__global__ __launch_bounds__(256) void gate_ln_kernel(
    const float* __restrict__ z, const float* __restrict__ gw,
    const float* __restrict__ gb, const float* __restrict__ ln_s,
    const float* __restrict__ ln_b, const float* __restrict__ b2,
    unsigned short* __restrict__ xn, int* __restrict__ counts,
    int* __restrict__ rows, float* __restrict__ g_out,
    float* __restrict__ logits)
{
    int wave = threadIdx.x >> 6;
    int lane = threadIdx.x & 63;
    int b = blockIdx.x * 4 + wave;
    if (b >= NB) return;

    const float* zr = z + (size_t)b * ND;
    float4 za = *reinterpret_cast<const float4*>(zr + lane * 8);
    float4 zb = *reinterpret_cast<const float4*>(zr + lane * 8 + 4);
    float zv[8] = {za.x, za.y, za.z, za.w, zb.x, zb.y, zb.z, zb.w};

    float sum = 0.f, ssq = 0.f;
#pragma unroll
    for (int k = 0; k < 8; ++k) { sum += zv[k]; ssq += zv[k] * zv[k]; }

    float acc[NE];
#pragma unroll
    for (int e = 0; e < NE; ++e) acc[e] = 0.f;

#pragma unroll
    for (int k = 0; k < 8; ++k) {
        int d = lane * 8 + k;
        const float4* gwp = reinterpret_cast<const float4*>(gw + d * NE);
        float4 q0 = gwp[0], q1 = gwp[1], q2 = gwp[2], q3 = gwp[3];
        float gvec[NE] = {q0.x, q0.y, q0.z, q0.w, q1.x, q1.y, q1.z, q1.w,
                          q2.x, q2.y, q2.z, q2.w, q3.x, q3.y, q3.z, q3.w};
        float zk = zv[k];
#pragma unroll
        for (int e = 0; e < NE; ++e) acc[e] = fmaf(zk, gvec[e], acc[e]);
    }

#pragma unroll
    for (int m = 32; m >= 1; m >>= 1) {
        sum += __shfl_xor(sum, m);
        ssq += __shfl_xor(ssq, m);
#pragma unroll
        for (int e = 0; e < NE; ++e) acc[e] += __shfl_xor(acc[e], m);
    }

    float mu = sum * (1.f / ND);
    float var = ssq * (1.f / ND) - mu * mu;
    float rstd = rsqrtf(var + LN_EPS);

    float mx = -1e30f;
#pragma unroll
    for (int e = 0; e < NE; ++e) { acc[e] += gb[e]; mx = fmaxf(mx, acc[e]); }
    float den = 0.f;
#pragma unroll
    for (int e = 0; e < NE; ++e) { acc[e] = __expf(acc[e] - mx); den += acc[e]; }
    float rden = 1.f / den;
#pragma unroll
    for (int e = 0; e < NE; ++e) acc[e] *= rden;

    int idx = 0; float best = acc[0];
#pragma unroll
    for (int e = 1; e < NE; ++e) { if (acc[e] > best) { best = acc[e]; idx = e; } }

    // xn = ((z-mu)*rstd)*ln_s[idx] + ln_b[idx], bf16 RNE
    const float* ls = ln_s + (size_t)idx * ND;
    const float* lb = ln_b + (size_t)idx * ND;
    float4 s0 = *reinterpret_cast<const float4*>(ls + lane * 8);
    float4 s1 = *reinterpret_cast<const float4*>(ls + lane * 8 + 4);
    float4 t0 = *reinterpret_cast<const float4*>(lb + lane * 8);
    float4 t1 = *reinterpret_cast<const float4*>(lb + lane * 8 + 4);
    float lsv[8] = {s0.x, s0.y, s0.z, s0.w, s1.x, s1.y, s1.z, s1.w};
    float lbv[8] = {t0.x, t0.y, t0.z, t0.w, t1.x, t1.y, t1.z, t1.w};
    unsigned short xb[8];
#pragma unroll
    for (int k = 0; k < 8; ++k) {
        float xv = (zv[k] - mu) * rstd * lsv[k] + lbv[k];
        xb[k] = bf16_rne(xv);
    }
    *reinterpret_cast<s8v*>(xn + (size_t)b * ND + lane * 8) =
        *reinterpret_cast<s8v*>(xb);

    float gval = acc[0];
#pragma unroll
    for (int e = 1; e < NE; ++e) if (lane == e) gval = acc[e];
    if (lane < NE) g_out[(size_t)b * NE + lane] = gval;

    if (lane == 0) {
        logits[b] = b2[idx];   // init; mfma_mlp accumulates on top
        int pos = atomicAdd(counts + idx, 1);
        rows[(size_t)idx * NB + pos] = b;
    }
}

// ---------------- Kernel W: w1 f32 [E][K][H] -> bf16 [E*NCH][CW][K] -------
// grid = NE*NCH*4 blocks; each block does 1/4 of the K rows of one slice.
__global__ __launch_bounds__(256) void w1_transpose(
    const float* __restrict__ w1, unsigned short* __restrict__ w1t)
{
    int bx = blockIdx.x;
    int sidx = bx >> 2;          // storage slice index = e*NCH + ch
    int kq = bx & 3;
    int e = sidx >> 4;
    int ch = sidx & 15;
    int t = threadIdx.x;
    int cl = t & 127;            // col within chunk
    int kh = t >> 7;             // 0..1
    int k0 = kq * 128 + kh * 64;

    const float* src = w1 + (size_t)e * ND * NH + (size_t)ch * CW + cl;
    unsigned short* dst = w1t + (size_t)sidx * (CW * ND) + (size_t)cl * ND;

#pragma unroll 4
    for (int k = k0; k < k0 + 64; k += 2) {
        float f0 = src[(size_t)k * NH];
        float f1 = src[(size_t)(k + 1) * NH];
        unsigned int u = (unsigned int)bf16_rne(f0) |
                         ((unsigned int)bf16_rne(f1) << 16);
        *reinterpret_cast<unsigned int*>(dst + k) = u;
    }
}

// ---------------- Kernel C: persistent-slice grouped MFMA GEMM ------------
// grid = 256: e = bid&15, ch = bid>>4 (XCD x serves experts {x, x+8} only).
// Block: stage w1t slice (128 KiB) into XOR-swizzled LDS once; each of 4
// waves streams 64-row tiles of the expert bucket through 16 K-steps of
// mfma_f32_16x16x32_bf16 (no barriers in the loop), then gelu + w2 dot +
// shuffle-reduce + atomicAdd into logits.
__global__ __launch_bounds__(256, 1) void mfma_mlp(
    const unsigned short* __restrict__ xn, const unsigned short* __restrict__ w1t,
    const float* __restrict__ b1, const float* __restrict__ w2,
    const int* __restrict__ counts, const int* __restrict__ rows,
    float* __restrict__ logits)
{
    __shared__ unsigned short lds_w[CW * ND];   // 131072 B

    int bid = blockIdx.x;
    int e  = bid & 15;
    int ch = bid >> 4;
    int sidx = e * NCH + ch;
    int tid = threadIdx.x;
    int lane = tid & 63;
    int wave = tid >> 6;

    // ---- stage slice into LDS with byte-XOR swizzle (col&7)<<4 ----
    const char* src = (const char*)(w1t + (size_t)sidx * (CW * ND));
    for (int i = tid; i < (CW * ND * 2) / 16; i += 256) {
        int o = i * 16;
        int d = o ^ (((o >> 10) & 7) << 4);
        *reinterpret_cast<s8v*>((char*)lds_w + d) =
            *reinterpret_cast<const s8v*>(src + o);
    }
    __syncthreads();

    int cnt = counts[e];
    const int* rl = rows + (size_t)e * NB;
    int c0 = ch * CW;

    // per-lane column constants (col = c0 + cf*16 + (lane&15))
    float b1v[8], w2v[8];
#pragma unroll
    for (int cf = 0; cf < 8; ++cf) {
        int col = c0 + cf * 16 + (lane & 15);
        b1v[cf] = b1[(size_t)e * NH + col];
        w2v[cf] = w2[(size_t)e * NH + col];
    }

    int g = lane >> 4;          // 0..3 k-group
    int s = (lane & 7) << 4;    // read-side swizzle

    for (int t = wave; t * 64 < cnt; t += 4) {
        int r0 = t * 64;
        const unsigned short* abase[4];
#pragma unroll
        for (int rf = 0; rf < 4; ++rf) {
            int rp = r0 + rf * 16 + (lane & 15);
            int rpc = rp < cnt ? rp : cnt - 1;
            abase[rf] = xn + (size_t)rl[rpc] * ND + g * 8;
        }

        f4v acc[4][8];
#pragma unroll
        for (int rf = 0; rf < 4; ++rf)
#pragma unroll
            for (int cf = 0; cf < 8; ++cf) acc[rf][cf] = (f4v){0.f, 0.f, 0.f, 0.f};

#pragma unroll
        for (int ks = 0; ks < 16; ++ks) {
            s8v a[4], b[8];
#pragma unroll
            for (int rf = 0; rf < 4; ++rf)
                a[rf] = *reinterpret_cast<const s8v*>(abase[rf] + ks * 32);
#pragma unroll
            for (int cf = 0; cf < 8; ++cf) {
                int col = cf * 16 + (lane & 15);
                int kbyte = ks * 64 + g * 16;
                int off = (col << 10) | (kbyte ^ s);
                b[cf] = *reinterpret_cast<const s8v*>((char*)lds_w + off);
            }
#pragma unroll
            for (int rf = 0; rf < 4; ++rf)
#pragma unroll
                for (int cf = 0; cf < 8; ++cf)
                    acc[rf][cf] = __builtin_amdgcn_mfma_f32_16x16x32_bf16(
                        a[rf], b[cf], acc[rf][cf], 0, 0, 0);
        }

        // ---- epilogue: bias + gelu(tanh-fast) + w2 dot + reduce + atomic ----
#pragma unroll
        for (int rf = 0; rf < 4; ++rf) {
            float pj[4] = {0.f, 0.f, 0.f, 0.f};
#pragma unroll
            for (int cf = 0; cf < 8; ++cf) {
#pragma unroll
                for (int j = 0; j < 4; ++j) {
                    float h = acc[rf][cf][j] + b1v[cf];
                    float u = h * (0.7978845608f + 0.0356774081f * h * h);
                    float ex = __expf(2.f * u);
                    float th = 1.f - 2.f / (ex + 1.f);
                    float gl = 0.5f * h * (1.f + th);
                    pj[j] = fmaf(gl, w2v[cf], pj[j]);
                }
            }
#pragma unroll
            for (int m = 1; m < 16; m <<= 1) {
#pragma unroll
                for (int j = 0; j < 4; ++j) pj[j] += __shfl_xor(pj[j], m);
            }
            if ((lane & 15) == 0) {
#pragma unroll
                for (int j = 0; j < 4; ++j) {
                    int rp = r0 + rf * 16 + g * 4 + j;
                    if (rp < cnt) atomicAdd(&logits[rl[rp]], pj[j]);
                }
            }
        }
    }
}

extern "C" void kernel_launch(void* const* d_in, const int* in_sizes, int n_in,
                              void* d_out, int out_size, void* d_ws, size_t ws_size,
                              hipStream_t stream) {
    const float* z    = (const float*)d_in[0];
    const float* gw   = (const float*)d_in[1];
    const float* gb   = (const float*)d_in[2];
    const float* ln_s = (const float*)d_in[3];
    const float* ln_b = (const float*)d_in[4];
    const float* w1   = (const float*)d_in[5];
    const float* b1   = (const float*)d_in[6];
    const float* w2   = (const float*)d_in[7];
    const float* b2   = (const float*)d_in[8];

    float* logits = (float*)d_out;            // [NB]
    float* g_out  = (float*)d_out + NB;       // [NB, NE]

    char* ws = (char*)d_ws;
    unsigned short* w1t = (unsigned short*)(ws + WS_W1T_OFF);
    unsigned short* xn  = (unsigned short*)(ws + WS_XN_OFF);
    int* cnts = (int*)(ws + WS_CNT_OFF);
    int* rowl = (int*)(ws + WS_ROWS_OFF);

    hipMemsetAsync(cnts, 0, 256, stream);

    w1_transpose<<<NE * NCH * 4, 256, 0, stream>>>(w1, w1t);
    gate_ln_kernel<<<NB / 4, 256, 0, stream>>>(z, gw, gb, ln_s, ln_b, b2,
                                               xn, cnts, rowl, g_out, logits);
    mfma_mlp<<<NE * NCH, 256, 0, stream>>>(xn, w1t, b1, w2, cnts, rowl, logits);
}

// Round 3
// 372.201 us; speedup vs baseline: 4.7054x; 1.1137x over previous
//
#include <hip/hip_runtime.h>
#include <math.h>

#define NB 16384
#define ND 512
#define NE 16
#define NH 2048
#define CW 64             // cols per chunk in mfma_mlp
#define NCH (NH / CW)     // 32 chunks
#define LN_EPS 1e-5f

typedef __attribute__((ext_vector_type(8))) short s8v;   // 8 bf16 (4 VGPR)
typedef __attribute__((ext_vector_type(4))) float f4v;   // mfma 16x16 acc

// ---- ws layout (bytes) ----
#define WS_XN_OFF    ((size_t)0)
#define WS_XN_BYTES  ((size_t)NB * ND * 2)                       // 16 MiB
#define WS_CNT_OFF   (WS_XN_OFF + WS_XN_BYTES)
#define WS_ROWS_OFF  (WS_CNT_OFF + 256)

__device__ __forceinline__ unsigned short bf16_rne(float f) {
    unsigned u = __float_as_uint(f);
    unsigned r = (u + 0x7fffu + ((u >> 16) & 1u)) >> 16;
    return (unsigned short)r;
}

// ---------------- Kernel 1: gate + softmax + argmax + LN + xn(bf16) -------
__global__ __launch_bounds__(256) void gate_ln_kernel(
    const float* __restrict__ z, const float* __restrict__ gw,
    const float* __restrict__ gb, const float* __restrict__ ln_s,
    const float* __restrict__ ln_b, const float* __restrict__ b2,
    unsigned short* __restrict__ xn, int* __restrict__ counts,
    int* __restrict__ rows, float* __restrict__ g_out,
    float* __restrict__ logits)
{
    int wave = threadIdx.x >> 6;
    int lane = threadIdx.x & 63;
    int b = blockIdx.x * 4 + wave;
    if (b >= NB) return;

    const float* zr = z + (size_t)b * ND;
    float4 za = *reinterpret_cast<const float4*>(zr + lane * 8);
    float4 zb = *reinterpret_cast<const float4*>(zr + lane * 8 + 4);
    float zv[8] = {za.x, za.y, za.z, za.w, zb.x, zb.y, zb.z, zb.w};

    float sum = 0.f, ssq = 0.f;
#pragma unroll
    for (int k = 0; k < 8; ++k) { sum += zv[k]; ssq += zv[k] * zv[k]; }

    float acc[NE];
#pragma unroll
    for (int e = 0; e < NE; ++e) acc[e] = 0.f;

#pragma unroll
    for (int k = 0; k < 8; ++k) {
        int d = lane * 8 + k;
        const float4* gwp = reinterpret_cast<const float4*>(gw + d * NE);
        float4 q0 = gwp[0], q1 = gwp[1], q2 = gwp[2], q3 = gwp[3];
        float gvec[NE] = {q0.x, q0.y, q0.z, q0.w, q1.x, q1.y, q1.z, q1.w,
                          q2.x, q2.y, q2.z, q2.w, q3.x, q3.y, q3.z, q3.w};
        float zk = zv[k];
#pragma unroll
        for (int e = 0; e < NE; ++e) acc[e] = fmaf(zk, gvec[e], acc[e]);
    }

#pragma unroll
    for (int m = 32; m >= 1; m >>= 1) {
        sum += __shfl_xor(sum, m);
        ssq += __shfl_xor(ssq, m);
#pragma unroll
        for (int e = 0; e < NE; ++e) acc[e] += __shfl_xor(acc[e], m);
    }

    float mu = sum * (1.f / ND);
    float var = ssq * (1.f / ND) - mu * mu;
    float rstd = rsqrtf(var + LN_EPS);

    float mx = -1e30f;
#pragma unroll
    for (int e = 0; e < NE; ++e) { acc[e] += gb[e]; mx = fmaxf(mx, acc[e]); }
    float den = 0.f;
#pragma unroll
    for (int e = 0; e < NE; ++e) { acc[e] = __expf(acc[e] - mx); den += acc[e]; }
    float rden = 1.f / den;
#pragma unroll
    for (int e = 0; e < NE; ++e) acc[e] *= rden;

    int idx = 0; float best = acc[0];
#pragma unroll
    for (int e = 1; e < NE; ++e) { if (acc[e] > best) { best = acc[e]; idx = e; } }

    const float* ls = ln_s + (size_t)idx * ND;
    const float* lb = ln_b + (size_t)idx * ND;
    float4 s0 = *reinterpret_cast<const float4*>(ls + lane * 8);
    float4 s1 = *reinterpret_cast<const float4*>(ls + lane * 8 + 4);
    float4 t0 = *reinterpret_cast<const float4*>(lb + lane * 8);
    float4 t1 = *reinterpret_cast<const float4*>(lb + lane * 8 + 4);
    float lsv[8] = {s0.x, s0.y, s0.z, s0.w, s1.x, s1.y, s1.z, s1.w};
    float lbv[8] = {t0.x, t0.y, t0.z, t0.w, t1.x, t1.y, t1.z, t1.w};
    unsigned short xb[8];
#pragma unroll
    for (int k = 0; k < 8; ++k) {
        float xv = (zv[k] - mu) * rstd * lsv[k] + lbv[k];
        xb[k] = bf16_rne(xv);
    }
    *reinterpret_cast<s8v*>(xn + (size_t)b * ND + lane * 8) =
        *reinterpret_cast<s8v*>(xb);

    float gval = acc[0];
#pragma unroll
    for (int e = 1; e < NE; ++e) if (lane == e) gval = acc[e];
    if (lane < NE) g_out[(size_t)b * NE + lane] = gval;

    if (lane == 0) {
        logits[b] = b2[idx];   // init; mfma_mlp accumulates on top
        int pos = atomicAdd(counts + idx, 1);
        rows[(size_t)idx * NB + pos] = b;
    }
}

// ---------------- Kernel 2: grouped MFMA MLP ------------------------------
// grid = NE*NCH = 512: e = bid&15 (expert->XCD pinning), ch = bid>>4.
// Block: stage 64-col w1 slice f32->bf16 transposed into swizzled LDS once
// (no transpose kernel, no extra HBM round-trip), then 4 waves stream
// 64-row tiles of the expert bucket: 16 K-steps x (4 A-glb + 4 B-lds +
// 16 MFMA), gelu + w2 dot + shuffle reduce + atomicAdd.
__global__ __launch_bounds__(256, 2) void mfma_mlp(
    const unsigned short* __restrict__ xn, const float* __restrict__ w1,
    const float* __restrict__ b1, const float* __restrict__ w2,
    const int* __restrict__ counts, const int* __restrict__ rows,
    float* __restrict__ logits)
{
    __shared__ char lds_b[CW * ND * 2];   // 65536 B, [col][k] bf16, swizzled

    int bid = blockIdx.x;
    int e  = bid & 15;
    int ch = bid >> 4;          // 0..31
    int c0 = ch * CW;
    int tid = threadIdx.x;
    int lane = tid & 63;
    int wave = tid >> 6;

    // ---- stage B: w1[e][k][c0+c] -> lds_b[c][2k ^ ((c&7)<<4)] -------------
    {
        int c  = tid & 63;
        int kq = tid >> 6;                      // 0..3 -> k range of 128
        const float* src = w1 + (size_t)e * ND * NH + c0 + c;
        char* dst = lds_b + c * 1024;
        int sw = (c & 7) << 4;
        for (int k0 = kq * 128; k0 < kq * 128 + 128; k0 += 8) {
            unsigned int u[4];
#pragma unroll
            for (int p = 0; p < 4; ++p) {
                float f0 = src[(size_t)(k0 + 2 * p) * NH];
                float f1 = src[(size_t)(k0 + 2 * p + 1) * NH];
                u[p] = (unsigned)bf16_rne(f0) | ((unsigned)bf16_rne(f1) << 16);
            }
            *reinterpret_cast<uint4*>(dst + ((k0 * 2) ^ sw)) =
                make_uint4(u[0], u[1], u[2], u[3]);
        }
    }
    __syncthreads();

    int cnt = counts[e];
    const int* rl = rows + (size_t)e * NB;

    float b1v[4], w2v[4];
    int bb[4];                  // precomputed LDS byte bases per cf
#pragma unroll
    for (int cf = 0; cf < 4; ++cf) {
        int col = cf * 16 + (lane & 15);
        b1v[cf] = b1[(size_t)e * NH + c0 + col];
        w2v[cf] = w2[(size_t)e * NH + c0 + col];
        bb[cf] = col * 1024;
    }
    int g = lane >> 4;
    int sw = (lane & 7) << 4;   // col&7 == lane&7 for all cf

    for (int t = wave; t * 64 < cnt; t += 4) {
        int r0 = t * 64;
        const unsigned short* abase[4];
#pragma unroll
        for (int rf = 0; rf < 4; ++rf) {
            int rp = r0 + rf * 16 + (lane & 15);
            int rpc = rp < cnt ? rp : cnt - 1;
            abase[rf] = xn + (size_t)rl[rpc] * ND + g * 8;
        }

        f4v acc[4][4];
#pragma unroll
        for (int rf = 0; rf < 4; ++rf)
#pragma unroll
            for (int cf = 0; cf < 4; ++cf) acc[rf][cf] = (f4v){0.f, 0.f, 0.f, 0.f};

#pragma unroll
        for (int ks = 0; ks < 16; ++ks) {
            s8v a[4], b[4];
#pragma unroll
            for (int rf = 0; rf < 4; ++rf)
                a[rf] = *reinterpret_cast<const s8v*>(abase[rf] + ks * 32);
            int kb = (ks * 64 + g * 16) ^ sw;
#pragma unroll
            for (int cf = 0; cf < 4; ++cf)
                b[cf] = *reinterpret_cast<const s8v*>(lds_b + bb[cf] + kb);
#pragma unroll
            for (int rf = 0; rf < 4; ++rf)
#pragma unroll
                for (int cf = 0; cf < 4; ++cf)
                    acc[rf][cf] = __builtin_amdgcn_mfma_f32_16x16x32_bf16(
                        a[rf], b[cf], acc[rf][cf], 0, 0, 0);
        }

        // ---- epilogue: bias + gelu + w2 dot + 16-lane reduce + atomic ----
#pragma unroll
        for (int rf = 0; rf < 4; ++rf) {
            float pj[4] = {0.f, 0.f, 0.f, 0.f};
#pragma unroll
            for (int cf = 0; cf < 4; ++cf) {
#pragma unroll
                for (int j = 0; j < 4; ++j) {
                    float h = acc[rf][cf][j] + b1v[cf];
                    float u = h * (0.7978845608f + 0.0356774081f * h * h);
                    float ex = __expf(2.f * u);
                    float th = 1.f - 2.f / (ex + 1.f);
                    float gl = 0.5f * h * (1.f + th);
                    pj[j] = fmaf(gl, w2v[cf], pj[j]);
                }
            }
#pragma unroll
            for (int m = 1; m < 16; m <<= 1) {
#pragma unroll
                for (int j = 0; j < 4; ++j) pj[j] += __shfl_xor(pj[j], m);
            }
            if ((lane & 15) == 0) {
#pragma unroll
                for (int j = 0; j < 4; ++j) {
                    int rp = r0 + rf * 16 + g * 4 + j;
                    if (rp < cnt) atomicAdd(&logits[rl[rp]], pj[j]);
                }
            }
        }
    }
}

extern "C" void kernel_launch(void* const* d_in, const int* in_sizes, int n_in,
                              void* d_out, int out_size, void* d_ws, size_t ws_size,
                              hipStream_t stream) {
    const float* z    = (const float*)d_in[0];
    const float* gw   = (const float*)d_in[1];
    const float* gb   = (const float*)d_in[2];
    const float* ln_s = (const float*)d_in[3];
    const float* ln_b = (const float*)d_in[4];
    const float* w1   = (const float*)d_in[5];
    const float* b1   = (const float*)d_in[6];
    const float* w2   = (const float*)d_in[7];
    const float* b2   = (const float*)d_in[8];

    float* logits = (float*)d_out;            // [NB]
    float* g_out  = (float*)d_out + NB;       // [NB, NE]

    char* ws = (char*)d_ws;
    unsigned short* xn = (unsigned short*)(ws + WS_XN_OFF);
    int* cnts = (int*)(ws + WS_CNT_OFF);
    int* rowl = (int*)(ws + WS_ROWS_OFF);

    hipMemsetAsync(cnts, 0, 256, stream);

    gate_ln_kernel<<<NB / 4, 256, 0, stream>>>(z, gw, gb, ln_s, ln_b, b2,
                                               xn, cnts, rowl, g_out, logits);
    mfma_mlp<<<NE * NCH, 256, 0, stream>>>(xn, w1, b1, w2, cnts, rowl, logits);
}